// Round 2
// baseline (1917.777 us; speedup 1.0000x reference)
//
#include <hip/hip_runtime.h>
#include <hip/hip_bf16.h>
#include <math.h>

// CrossAttentionFusion on MI355X.
// softmax over one key == 1  =>  mha1(q_in, kv_in) = (kv_in@Wv.T+bv)@Wo.T+bo.
// Pipeline: 9 bf16-MFMA GEMMs (FFNs row-chunked x4) + 3 f32 layernorms.
// Workspace budget ~121 MB (FFN hidden chunked, residuals reused as bf16).

typedef unsigned short u16;
typedef __bf16 bf16_t;
typedef bf16_t bf16x8 __attribute__((ext_vector_type(8)));
typedef float f32x4 __attribute__((ext_vector_type(4)));

#define BROWS 16384   // batch
#define EDIM  768
#define FCHUNK 4096   // FFN row-chunk

__device__ __forceinline__ u16 f2bf(float f) {
    union { float f; unsigned u; } v; v.f = f;
    return (u16)((v.u + 0x7FFFu + ((v.u >> 16) & 1u)) >> 16);  // RNE
}
__device__ __forceinline__ float bf2f(u16 h) {
    union { unsigned u; float f; } v; v.u = ((unsigned)h) << 16;
    return v.f;
}

__device__ __forceinline__ float gelu_f(float x) {
    return 0.5f * x * (1.0f + erff(x * 0.70710678118654752f));  // exact gelu
}

// async global->LDS, 16B/lane. LDS dest is wave-uniform base + lane*16.
__device__ __forceinline__ void gld16(const u16* g, u16* l) {
    __builtin_amdgcn_global_load_lds(
        (__attribute__((address_space(1))) void*)g,
        (__attribute__((address_space(3))) void*)l, 16, 0, 0);
}

__global__ void __launch_bounds__(256) f32_to_bf16_k(const float* __restrict__ s,
                                                     u16* __restrict__ d, int n4) {
    int i = blockIdx.x * 256 + threadIdx.x;
    if (i < n4) {
        float4 v = ((const float4*)s)[i];
        ushort4 o;
        o.x = f2bf(v.x); o.y = f2bf(v.y); o.z = f2bf(v.z); o.w = f2bf(v.w);
        ((ushort4*)d)[i] = o;
    }
}

// C[m,n] = sum_k A[m,k] * W[n,k]  (+bias, +f32 or bf16 residual, opt gelu)
// A: bf16 [M,lda], W: bf16 [N,K] row-major. 128x128 tile, BK=32,
// 4 waves in 2x2, each wave 64x64 via 4x4 mfma_f32_16x16x32_bf16.
__global__ void __launch_bounds__(256) gemm_bt(
    const u16* __restrict__ A, int lda,
    const u16* __restrict__ W,
    const float* __restrict__ bias,
    const float* __restrict__ R, int ldr,      // f32 residual (or null)
    const u16* __restrict__ Rb, int ldrb,      // bf16 residual (or null)
    float* __restrict__ Cf, int ldcf,
    u16* __restrict__ Cb, int ldcb,
    int K, int do_gelu)
{
    __shared__ alignas(16) u16 sA[128 * 32];  // [row][k], unpadded (global_load_lds)
    __shared__ alignas(16) u16 sB[128 * 32];

    const int tid  = threadIdx.x;
    const int lane = tid & 63;
    const int wave = tid >> 6;
    const int wm = wave >> 1;      // 0..1
    const int wn = wave & 1;       // 0..1
    const long m0 = (long)blockIdx.y * 128;
    const long n0 = (long)blockIdx.x * 128;

    // staging: each wave fills 2 chunks of 16 rows (1KB each) per tile
    const int r  = lane >> 2;      // 0..15 row within chunk
    const int cb = lane & 3;       // 16B column block
    const int c0 = wave * 2, c1 = wave * 2 + 1;
    const u16* gA0 = A + (m0 + c0 * 16 + r) * (long)lda + cb * 8;
    const u16* gA1 = A + (m0 + c1 * 16 + r) * (long)lda + cb * 8;
    const u16* gB0 = W + (n0 + c0 * 16 + r) * (long)K + cb * 8;
    const u16* gB1 = W + (n0 + c1 * 16 + r) * (long)K + cb * 8;
    u16* lA0 = sA + c0 * 512;
    u16* lA1 = sA + c1 * 512;
    u16* lB0 = sB + c0 * 512;
    u16* lB1 = sB + c1 * 512;

    // LDS fragment read offsets (constant across K)
    const int quad = lane >> 4;    // 0..3 -> k = quad*8 + j
    const int l16  = lane & 15;    // m (A) / n (B) index
    int offA[4], offB[4];
#pragma unroll
    for (int t = 0; t < 4; t++) {
        offA[t] = (wm * 64 + t * 16 + l16) * 32 + quad * 8;
        offB[t] = (wn * 64 + t * 16 + l16) * 32 + quad * 8;
    }

    f32x4 acc[4][4];
#pragma unroll
    for (int i = 0; i < 4; i++)
#pragma unroll
        for (int j = 0; j < 4; j++) {
            f32x4 z = {0.f, 0.f, 0.f, 0.f};
            acc[i][j] = z;
        }

    for (int k0 = 0; k0 < K; k0 += 32) {
        gld16(gA0, lA0); gld16(gA1, lA1);
        gld16(gB0, lB0); gld16(gB1, lB1);
        gA0 += 32; gA1 += 32; gB0 += 32; gB1 += 32;
        __syncthreads();   // drains vmcnt -> tiles visible
        bf16x8 af[4], bfr[4];
#pragma unroll
        for (int t = 0; t < 4; t++) af[t]  = *(const bf16x8*)(sA + offA[t]);
#pragma unroll
        for (int t = 0; t < 4; t++) bfr[t] = *(const bf16x8*)(sB + offB[t]);
#pragma unroll
        for (int mt = 0; mt < 4; mt++)
#pragma unroll
            for (int nt = 0; nt < 4; nt++)
                acc[mt][nt] = __builtin_amdgcn_mfma_f32_16x16x32_bf16(
                    af[mt], bfr[nt], acc[mt][nt], 0, 0, 0);
        __syncthreads();   // reads done before next staging overwrites
    }

    // epilogue: C/D layout col = lane&15, row = quad*4 + reg  [m89/m91]
#pragma unroll
    for (int mt = 0; mt < 4; mt++) {
#pragma unroll
        for (int nt = 0; nt < 4; nt++) {
            const long col = n0 + wn * 64 + nt * 16 + l16;
            const float bv = bias ? bias[col] : 0.0f;
#pragma unroll
            for (int rr = 0; rr < 4; rr++) {
                const long row = m0 + wm * 64 + mt * 16 + quad * 4 + rr;
                float v = acc[mt][nt][rr] + bv;
                if (R)  v += R[row * (long)ldr + col];
                if (Rb) v += bf2f(Rb[row * (long)ldrb + col]);
                if (do_gelu) v = gelu_f(v);
                if (Cf) Cf[row * (long)ldcf + col] = v;
                if (Cb) Cb[row * (long)ldcb + col] = f2bf(v);
            }
        }
    }
}

// LayerNorm over 768 cols, one block/row; optional gelu; f32 and/or bf16 out.
__global__ void __launch_bounds__(256) ln_k(
    const float* __restrict__ X,
    const float* __restrict__ g,
    const float* __restrict__ b,
    float* __restrict__ Yf,
    u16* __restrict__ Yb, int ldyb,
    int do_gelu)
{
    const int row = blockIdx.x;
    const int tid = threadIdx.x;
    const float* x = X + (long)row * EDIM;
    float v0 = x[tid], v1 = x[tid + 256], v2 = x[tid + 512];
    float s  = v0 + v1 + v2;
    float s2 = v0 * v0 + v1 * v1 + v2 * v2;
#pragma unroll
    for (int o = 32; o > 0; o >>= 1) {
        s  += __shfl_down(s,  o, 64);
        s2 += __shfl_down(s2, o, 64);
    }
    __shared__ float red[8];
    __shared__ float mb[2];
    const int wave = tid >> 6, lane = tid & 63;
    if (lane == 0) { red[wave] = s; red[4 + wave] = s2; }
    __syncthreads();
    if (tid == 0) {
        float S  = red[0] + red[1] + red[2] + red[3];
        float S2 = red[4] + red[5] + red[6] + red[7];
        float mean = S * (1.0f / 768.0f);
        float var  = S2 * (1.0f / 768.0f) - mean * mean;
        mb[0] = mean;
        mb[1] = rsqrtf(var + 1e-5f);
    }
    __syncthreads();
    const float mean = mb[0], inv = mb[1];
#pragma unroll
    for (int j = 0; j < 3; j++) {
        const int c = tid + j * 256;
        const float v = (j == 0 ? v0 : (j == 1 ? v1 : v2));
        float y = (v - mean) * inv * g[c] + b[c];
        if (do_gelu) y = gelu_f(y);
        if (Yf) Yf[(long)row * EDIM + c] = y;
        if (Yb) Yb[(long)row * (long)ldyb + c] = f2bf(y);
    }
}

extern "C" void kernel_launch(void* const* d_in, const int* in_sizes, int n_in,
                              void* d_out, int out_size, void* d_ws, size_t ws_size,
                              hipStream_t stream) {
    (void)in_sizes; (void)n_in; (void)out_size; (void)ws_size;
    const float* image    = (const float*)d_in[0];
    const float* text     = (const float*)d_in[1];
    const float* it_Wv    = (const float*)d_in[4];
    const float* it_Wo    = (const float*)d_in[5];
    const float* it_bv    = (const float*)d_in[8];
    const float* it_bo    = (const float*)d_in[9];
    const float* ti_Wv    = (const float*)d_in[12];
    const float* ti_Wo    = (const float*)d_in[13];
    const float* ti_bv    = (const float*)d_in[16];
    const float* ti_bo    = (const float*)d_in[17];
    const float* ln_img_g = (const float*)d_in[18];
    const float* ln_img_b = (const float*)d_in[19];
    const float* ln_txt_g = (const float*)d_in[20];
    const float* ln_txt_b = (const float*)d_in[21];
    const float* fp_ln_g  = (const float*)d_in[22];
    const float* fp_ln_b  = (const float*)d_in[23];
    const float* fi_W1    = (const float*)d_in[24];
    const float* fi_b1    = (const float*)d_in[25];
    const float* fi_W2    = (const float*)d_in[26];
    const float* fi_b2    = (const float*)d_in[27];
    const float* ft_W1    = (const float*)d_in[28];
    const float* ft_b1    = (const float*)d_in[29];
    const float* ft_W2    = (const float*)d_in[30];
    const float* ft_b2    = (const float*)d_in[31];
    const float* fp_W     = (const float*)d_in[32];
    const float* fp_b     = (const float*)d_in[33];

    char* ws = (char*)d_ws;
    size_t off = 0;
    auto alloc = [&](size_t bytes) {
        char* p = ws + off; off += (bytes + 255) & ~(size_t)255; return p;
    };
    // bf16 weights (~25 MB, live whole call)
    u16* wv_it = (u16*)alloc((size_t)768 * 768 * 2);
    u16* wo_it = (u16*)alloc((size_t)768 * 768 * 2);
    u16* wv_ti = (u16*)alloc((size_t)768 * 768 * 2);
    u16* wo_ti = (u16*)alloc((size_t)768 * 768 * 2);
    u16* w1i   = (u16*)alloc((size_t)3072 * 768 * 2);
    u16* w2i   = (u16*)alloc((size_t)768 * 3072 * 2);
    u16* w1t   = (u16*)alloc((size_t)3072 * 768 * 2);
    u16* w2t   = (u16*)alloc((size_t)768 * 3072 * 2);
    u16* wp    = (u16*)alloc((size_t)768 * 1536 * 2);
    // activations (~96 MB)
    u16* vbuf  = (u16*)alloc((size_t)BROWS * 768 * 2);   // v / post-LN bf16
    u16* fused = (u16*)alloc((size_t)BROWS * 1536 * 2);  // [img | txt] bf16
    u16* hbuf  = (u16*)alloc((size_t)FCHUNK * 3072 * 2); // FFN hidden (chunked)
    u16* text_bf = hbuf;                                 // alias: disjoint lifetime
    float* sbuf  = (float*)d_out;                        // f32 pre-LN scratch

    auto conv = [&](const float* src, u16* dst, long n) {
        int n4 = (int)(n / 4);
        f32_to_bf16_k<<<dim3((n4 + 255) / 256), dim3(256), 0, stream>>>(src, dst, n4);
    };
    auto gemm = [&](const u16* A, int lda, const u16* W, int M, int N, int K,
                    const float* bias, const float* R, int ldr,
                    const u16* Rb, int ldrb,
                    float* Cf, int ldcf, u16* Cb, int ldcb, int dg) {
        gemm_bt<<<dim3(N / 128, M / 128), dim3(256), 0, stream>>>(
            A, lda, W, bias, R, ldr, Rb, ldrb, Cf, ldcf, Cb, ldcb, K, dg);
    };
    auto ln = [&](const float* X, const float* gg, const float* bb,
                  float* Yf, u16* Yb, int ldyb, int dg) {
        ln_k<<<dim3(BROWS), dim3(256), 0, stream>>>(X, gg, bb, Yf, Yb, ldyb, dg);
    };
    // FFN (768 -> gelu(3072) -> 768 + resid), row-chunked to bound hbuf
    auto ffn = [&](const u16* xin, const u16* W1, const float* b1,
                   const u16* W2, const float* b2, u16* outp, int ldout) {
        for (int c = 0; c < BROWS / FCHUNK; c++) {
            const u16* xc = xin + (size_t)c * FCHUNK * 768;
            gemm(xc, 768, W1, FCHUNK, 3072, 768, b1,
                 nullptr, 0, nullptr, 0, nullptr, 0, hbuf, 3072, 1);
            gemm(hbuf, 3072, W2, FCHUNK, 768, 3072, b2,
                 nullptr, 0, xc, 768,
                 nullptr, 0, outp + (size_t)c * FCHUNK * ldout, ldout, 0);
        }
    };

    // weight + input conversion
    conv(it_Wv, wv_it, 768 * 768);
    conv(it_Wo, wo_it, 768 * 768);
    conv(ti_Wv, wv_ti, 768 * 768);
    conv(ti_Wo, wo_ti, 768 * 768);
    conv(fi_W1, w1i, 3072L * 768);
    conv(fi_W2, w2i, 768L * 3072);
    conv(ft_W1, w1t, 3072L * 768);
    conv(ft_W2, w2t, 768L * 3072);
    conv(fp_W,  wp,  768L * 1536);
    conv(text,  text_bf, (long)BROWS * 768);

    // image path: v = text@Wv.T+bv ; att = v@Wo.T+bo + image ; LN1
    gemm(text_bf, 768, wv_it, BROWS, 768, 768, it_bv,
         nullptr, 0, nullptr, 0, nullptr, 0, vbuf, 768, 0);
    gemm(vbuf, 768, wo_it, BROWS, 768, 768, it_bo,
         image, 768, nullptr, 0, sbuf, 768, nullptr, 0, 0);
    ln(sbuf, ln_img_g, ln_img_b, nullptr, vbuf, 768, 0);
    // image FFN -> fused[:, :768]
    ffn(vbuf, w1i, fi_b1, w2i, fi_b2, fused, 1536);
    // text path: kv = post-FFN img (fused left half)
    gemm(fused, 1536, wv_ti, BROWS, 768, 768, ti_bv,
         nullptr, 0, nullptr, 0, nullptr, 0, vbuf, 768, 0);
    gemm(vbuf, 768, wo_ti, BROWS, 768, 768, ti_bo,
         text, 768, nullptr, 0, sbuf, 768, nullptr, 0, 0);
    ln(sbuf, ln_txt_g, ln_txt_b, nullptr, vbuf, 768, 0);
    // text FFN -> fused[:, 768:]
    ffn(vbuf, w1t, ft_b1, w2t, ft_b2, fused + 768, 1536);
    // final projection + LN + gelu (in-place on d_out)
    gemm(fused, 1536, wp, BROWS, 768, 1536, fp_b,
         nullptr, 0, nullptr, 0, sbuf, 768, nullptr, 0, 0);
    ln(sbuf, fp_ln_g, fp_ln_b, (float*)d_out, nullptr, 0, 1);
}

// Round 3
// 1401.594 us; speedup vs baseline: 1.3683x; 1.3683x over previous
//
#include <hip/hip_runtime.h>
#include <hip/hip_bf16.h>
#include <math.h>

// CrossAttentionFusion on MI355X.
// softmax over one key == 1  =>  mha1(q_in, kv) = kv@Wv.T@Wo.T + bv@Wo.T + bo
//                                              = kv@Wc.T + bc,  Wc = Wo@Wv (fused once).
// Pipeline: 2 tiny weight-combine GEMMs + 7 bf16-MFMA GEMMs + 3 f32 layernorms.
// GEMM K-loop is double-buffered (prefetch into alternate LDS buffer before
// compute phase) so the __syncthreads vmcnt-drain overlaps the MFMA phase.

typedef unsigned short u16;
typedef __bf16 bf16_t;
typedef bf16_t bf16x8 __attribute__((ext_vector_type(8)));
typedef float f32x4 __attribute__((ext_vector_type(4)));

#define BROWS 16384   // batch
#define EDIM  768

__device__ __forceinline__ u16 f2bf(float f) {
    union { float f; unsigned u; } v; v.f = f;
    return (u16)((v.u + 0x7FFFu + ((v.u >> 16) & 1u)) >> 16);  // RNE
}
__device__ __forceinline__ float bf2f(u16 h) {
    union { unsigned u; float f; } v; v.u = ((unsigned)h) << 16;
    return v.f;
}
__device__ __forceinline__ float gelu_f(float x) {
    return 0.5f * x * (1.0f + erff(x * 0.70710678118654752f));  // exact gelu
}

// async global->LDS, 16B/lane. LDS dest is wave-uniform base + lane*16.
__device__ __forceinline__ void gld16(const u16* g, u16* l) {
    __builtin_amdgcn_global_load_lds(
        (__attribute__((address_space(1))) void*)g,
        (__attribute__((address_space(3))) void*)l, 16, 0, 0);
}

__global__ void __launch_bounds__(256) f32_to_bf16_k(const float* __restrict__ s,
                                                     u16* __restrict__ d, int n4) {
    int i = blockIdx.x * 256 + threadIdx.x;
    if (i < n4) {
        float4 v = ((const float4*)s)[i];
        ushort4 o;
        o.x = f2bf(v.x); o.y = f2bf(v.y); o.z = f2bf(v.z); o.w = f2bf(v.w);
        ((ushort4*)d)[i] = o;
    }
}

// D[c,r] = bf16(S[r,c]) — transpose-convert (for Wv.T in the weight combine).
__global__ void __launch_bounds__(256) f32_to_bf16_T_k(const float* __restrict__ S,
                                                       u16* __restrict__ D,
                                                       int R, int C) {
    __shared__ float t[32][33];
    const int r0 = blockIdx.y * 32, c0 = blockIdx.x * 32;
    const int tx = threadIdx.x & 31, ty = threadIdx.x >> 5;  // ty 0..7
#pragma unroll
    for (int i = ty; i < 32; i += 8) t[i][tx] = S[(long)(r0 + i) * C + c0 + tx];
    __syncthreads();
#pragma unroll
    for (int i = ty; i < 32; i += 8) D[(long)(c0 + i) * R + r0 + tx] = f2bf(t[tx][i]);
}

// bc[n] = bo[n] + dot(Wo[n,:], bv)   (f32, one wave per output row)
__global__ void __launch_bounds__(256) bias_comb_k(const float* __restrict__ Wo,
                                                   const float* __restrict__ bv,
                                                   const float* __restrict__ bo,
                                                   float* __restrict__ bc, int K) {
    const int n = blockIdx.x * 4 + (threadIdx.x >> 6);
    const int lane = threadIdx.x & 63;
    float s = 0.f;
    for (int k = lane; k < K; k += 64) s += Wo[(long)n * K + k] * bv[k];
#pragma unroll
    for (int o = 32; o > 0; o >>= 1) s += __shfl_down(s, o, 64);
    if (lane == 0) bc[n] = s + bo[n];
}

// C[m,n] = sum_k A[m,k] * W[n,k]  (+bias, +f32 or bf16 residual, opt gelu)
// A: bf16 [M,lda], W: bf16 [N,K] row-major. 128x128 tile, BK=32, double-buffered
// LDS. 4 waves in 2x2, each wave 64x64 via 4x4 mfma_f32_16x16x32_bf16.
__global__ void __launch_bounds__(256) gemm_bt(
    const u16* __restrict__ A, int lda,
    const u16* __restrict__ W,
    const float* __restrict__ bias,
    const float* __restrict__ R, int ldr,      // f32 residual (or null)
    const u16* __restrict__ Rb, int ldrb,      // bf16 residual (or null)
    float* __restrict__ Cf, int ldcf,
    u16* __restrict__ Cb, int ldcb,
    int K, int do_gelu)
{
    __shared__ alignas(16) u16 sA[2][128 * 32];  // [buf][row*32+k], unpadded
    __shared__ alignas(16) u16 sB[2][128 * 32];

    const int tid  = threadIdx.x;
    const int lane = tid & 63;
    const int wave = tid >> 6;
    const int wm = wave >> 1;      // 0..1
    const int wn = wave & 1;       // 0..1
    const long m0 = (long)blockIdx.y * 128;
    const long n0 = (long)blockIdx.x * 128;

    // staging: each wave fills 2 chunks of 16 rows (1KB each) per tile per matrix
    const int r  = lane >> 2;      // 0..15 row within chunk
    const int cb = lane & 3;       // 16B column block
    const int c0 = wave * 2, c1 = wave * 2 + 1;
    const u16* gA0 = A + (m0 + c0 * 16 + r) * (long)lda + cb * 8;
    const u16* gA1 = A + (m0 + c1 * 16 + r) * (long)lda + cb * 8;
    const u16* gB0 = W + (n0 + c0 * 16 + r) * (long)K + cb * 8;
    const u16* gB1 = W + (n0 + c1 * 16 + r) * (long)K + cb * 8;

    auto stage = [&](int buf, int kk) {
        gld16(gA0 + kk, sA[buf] + c0 * 512);
        gld16(gA1 + kk, sA[buf] + c1 * 512);
        gld16(gB0 + kk, sB[buf] + c0 * 512);
        gld16(gB1 + kk, sB[buf] + c1 * 512);
    };

    // LDS fragment read offsets (constant across K)
    const int quad = lane >> 4;    // 0..3 -> k = quad*8 + j
    const int l16  = lane & 15;    // m (A) / n (B) index
    int offA[4], offB[4];
#pragma unroll
    for (int t = 0; t < 4; t++) {
        offA[t] = (wm * 64 + t * 16 + l16) * 32 + quad * 8;
        offB[t] = (wn * 64 + t * 16 + l16) * 32 + quad * 8;
    }

    f32x4 acc[4][4];
#pragma unroll
    for (int i = 0; i < 4; i++)
#pragma unroll
        for (int j = 0; j < 4; j++) {
            f32x4 z = {0.f, 0.f, 0.f, 0.f};
            acc[i][j] = z;
        }

    stage(0, 0);
    __syncthreads();               // prologue tile visible
    int buf = 0;
    for (int k0 = 0; k0 < K; k0 += 32) {
        const int nk = k0 + 32;
        if (nk < K) stage(buf ^ 1, nk);   // async prefetch, overlaps compute below
        bf16x8 af[4], bfr[4];
#pragma unroll
        for (int t = 0; t < 4; t++) af[t]  = *(const bf16x8*)(sA[buf] + offA[t]);
#pragma unroll
        for (int t = 0; t < 4; t++) bfr[t] = *(const bf16x8*)(sB[buf] + offB[t]);
#pragma unroll
        for (int mt = 0; mt < 4; mt++)
#pragma unroll
            for (int nt = 0; nt < 4; nt++)
                acc[mt][nt] = __builtin_amdgcn_mfma_f32_16x16x32_bf16(
                    af[mt], bfr[nt], acc[mt][nt], 0, 0, 0);
        __syncthreads();           // drains prefetch + guards buffer reuse
        buf ^= 1;
    }

    // epilogue: C/D layout col = lane&15, row = quad*4 + reg  [m89/m91]
#pragma unroll
    for (int mt = 0; mt < 4; mt++) {
#pragma unroll
        for (int nt = 0; nt < 4; nt++) {
            const long col = n0 + wn * 64 + nt * 16 + l16;
            const float bv = bias ? bias[col] : 0.0f;
#pragma unroll
            for (int rr = 0; rr < 4; rr++) {
                const long row = m0 + wm * 64 + mt * 16 + quad * 4 + rr;
                float v = acc[mt][nt][rr] + bv;
                if (R)  v += R[row * (long)ldr + col];
                if (Rb) v += bf2f(Rb[row * (long)ldrb + col]);
                if (do_gelu) v = gelu_f(v);
                if (Cf) Cf[row * (long)ldcf + col] = v;
                if (Cb) Cb[row * (long)ldcb + col] = f2bf(v);
            }
        }
    }
}

// LayerNorm over 768 cols, one block/row; optional gelu; f32 and/or bf16 out.
__global__ void __launch_bounds__(256) ln_k(
    const float* __restrict__ X,
    const float* __restrict__ g,
    const float* __restrict__ b,
    float* __restrict__ Yf,
    u16* __restrict__ Yb, int ldyb,
    int do_gelu)
{
    const int row = blockIdx.x;
    const int tid = threadIdx.x;
    const float* x = X + (long)row * EDIM;
    float v0 = x[tid], v1 = x[tid + 256], v2 = x[tid + 512];
    float s  = v0 + v1 + v2;
    float s2 = v0 * v0 + v1 * v1 + v2 * v2;
#pragma unroll
    for (int o = 32; o > 0; o >>= 1) {
        s  += __shfl_down(s,  o, 64);
        s2 += __shfl_down(s2, o, 64);
    }
    __shared__ float red[8];
    __shared__ float mb[2];
    const int wave = tid >> 6, lane = tid & 63;
    if (lane == 0) { red[wave] = s; red[4 + wave] = s2; }
    __syncthreads();
    if (tid == 0) {
        float S  = red[0] + red[1] + red[2] + red[3];
        float S2 = red[4] + red[5] + red[6] + red[7];
        float mean = S * (1.0f / 768.0f);
        float var  = S2 * (1.0f / 768.0f) - mean * mean;
        mb[0] = mean;
        mb[1] = rsqrtf(var + 1e-5f);
    }
    __syncthreads();
    const float mean = mb[0], inv = mb[1];
#pragma unroll
    for (int j = 0; j < 3; j++) {
        const int c = tid + j * 256;
        const float v = (j == 0 ? v0 : (j == 1 ? v1 : v2));
        float y = (v - mean) * inv * g[c] + b[c];
        if (do_gelu) y = gelu_f(y);
        if (Yf) Yf[(long)row * EDIM + c] = y;
        if (Yb) Yb[(long)row * (long)ldyb + c] = f2bf(y);
    }
}

extern "C" void kernel_launch(void* const* d_in, const int* in_sizes, int n_in,
                              void* d_out, int out_size, void* d_ws, size_t ws_size,
                              hipStream_t stream) {
    (void)in_sizes; (void)n_in; (void)out_size;
    const float* image    = (const float*)d_in[0];
    const float* text     = (const float*)d_in[1];
    const float* it_Wv    = (const float*)d_in[4];
    const float* it_Wo    = (const float*)d_in[5];
    const float* it_bv    = (const float*)d_in[8];
    const float* it_bo    = (const float*)d_in[9];
    const float* ti_Wv    = (const float*)d_in[12];
    const float* ti_Wo    = (const float*)d_in[13];
    const float* ti_bv    = (const float*)d_in[16];
    const float* ti_bo    = (const float*)d_in[17];
    const float* ln_img_g = (const float*)d_in[18];
    const float* ln_img_b = (const float*)d_in[19];
    const float* ln_txt_g = (const float*)d_in[20];
    const float* ln_txt_b = (const float*)d_in[21];
    const float* fp_ln_g  = (const float*)d_in[22];
    const float* fp_ln_b  = (const float*)d_in[23];
    const float* fi_W1    = (const float*)d_in[24];
    const float* fi_b1    = (const float*)d_in[25];
    const float* fi_W2    = (const float*)d_in[26];
    const float* fi_b2    = (const float*)d_in[27];
    const float* ft_W1    = (const float*)d_in[28];
    const float* ft_b1    = (const float*)d_in[29];
    const float* ft_W2    = (const float*)d_in[30];
    const float* ft_b2    = (const float*)d_in[31];
    const float* fp_W     = (const float*)d_in[32];
    const float* fp_b     = (const float*)d_in[33];

    char* ws = (char*)d_ws;
    size_t off = 0;
    auto alloc = [&](size_t bytes) {
        char* p = ws + off; off += (bytes + 255) & ~(size_t)255; return p;
    };
    // bf16 weights (~28 MB, live whole call)
    u16* wo_it = (u16*)alloc((size_t)768 * 768 * 2);   // Wo bf16 (combine input)
    u16* wvT_it= (u16*)alloc((size_t)768 * 768 * 2);   // Wv.T bf16
    u16* wc_it = (u16*)alloc((size_t)768 * 768 * 2);   // Wo@Wv bf16
    u16* wo_ti = (u16*)alloc((size_t)768 * 768 * 2);
    u16* wvT_ti= (u16*)alloc((size_t)768 * 768 * 2);
    u16* wc_ti = (u16*)alloc((size_t)768 * 768 * 2);
    u16* w1i   = (u16*)alloc((size_t)3072 * 768 * 2);
    u16* w2i   = (u16*)alloc((size_t)768 * 3072 * 2);
    u16* w1t   = (u16*)alloc((size_t)3072 * 768 * 2);
    u16* w2t   = (u16*)alloc((size_t)768 * 3072 * 2);
    u16* wp    = (u16*)alloc((size_t)768 * 1536 * 2);
    float* bc_it = (float*)alloc(768 * 4);
    float* bc_ti = (float*)alloc(768 * 4);
    // activations
    u16* vbuf  = (u16*)alloc((size_t)BROWS * 768 * 2);   // post-LN bf16
    u16* fused = (u16*)alloc((size_t)BROWS * 1536 * 2);  // [img | txt] bf16
    u16* text_bf = fused;     // alias: text_bf dead before fused is written
    // FFN hidden: adaptive chunk size (largest that fits ws_size)
    int fch = 16384;
    while (fch > 2048 && off + (size_t)fch * 3072 * 2 > ws_size) fch >>= 1;
    u16* hbuf = (u16*)alloc((size_t)fch * 3072 * 2);
    float* sbuf = (float*)d_out;                         // f32 pre-LN scratch

    auto conv = [&](const float* src, u16* dst, long n) {
        int n4 = (int)(n / 4);
        f32_to_bf16_k<<<dim3((n4 + 255) / 256), dim3(256), 0, stream>>>(src, dst, n4);
    };
    auto gemm = [&](const u16* A, int lda, const u16* W, int M, int N, int K,
                    const float* bias, const float* R, int ldr,
                    const u16* Rb, int ldrb,
                    float* Cf, int ldcf, u16* Cb, int ldcb, int dg) {
        gemm_bt<<<dim3(N / 128, M / 128), dim3(256), 0, stream>>>(
            A, lda, W, bias, R, ldr, Rb, ldrb, Cf, ldcf, Cb, ldcb, K, dg);
    };
    auto ln = [&](const float* X, const float* gg, const float* bb,
                  float* Yf, u16* Yb, int ldyb, int dg) {
        ln_k<<<dim3(BROWS), dim3(256), 0, stream>>>(X, gg, bb, Yf, Yb, ldyb, dg);
    };
    auto ffn = [&](const u16* xin, const u16* W1, const float* b1,
                   const u16* W2, const float* b2, u16* outp, int ldout) {
        for (int c = 0; c < BROWS / fch; c++) {
            const u16* xc = xin + (size_t)c * fch * 768;
            gemm(xc, 768, W1, fch, 3072, 768, b1,
                 nullptr, 0, nullptr, 0, nullptr, 0, hbuf, 3072, 1);
            gemm(hbuf, 3072, W2, fch, 768, 3072, b2,
                 nullptr, 0, xc, 768,
                 nullptr, 0, outp + (size_t)c * fch * ldout, ldout, 0);
        }
    };

    // ---- weight prep: Wc = Wo@Wv (bf16), bc = Wo@bv + bo (f32) ----
    conv(it_Wo, wo_it, 768 * 768);
    f32_to_bf16_T_k<<<dim3(24, 24), dim3(256), 0, stream>>>(it_Wv, wvT_it, 768, 768);
    gemm(wo_it, 768, wvT_it, 768, 768, 768, nullptr,
         nullptr, 0, nullptr, 0, nullptr, 0, wc_it, 768, 0);
    bias_comb_k<<<dim3(192), dim3(256), 0, stream>>>(it_Wo, it_bv, it_bo, bc_it, 768);
    conv(ti_Wo, wo_ti, 768 * 768);
    f32_to_bf16_T_k<<<dim3(24, 24), dim3(256), 0, stream>>>(ti_Wv, wvT_ti, 768, 768);
    gemm(wo_ti, 768, wvT_ti, 768, 768, 768, nullptr,
         nullptr, 0, nullptr, 0, nullptr, 0, wc_ti, 768, 0);
    bias_comb_k<<<dim3(192), dim3(256), 0, stream>>>(ti_Wo, ti_bv, ti_bo, bc_ti, 768);
    conv(fi_W1, w1i, 3072L * 768);
    conv(fi_W2, w2i, 768L * 3072);
    conv(ft_W1, w1t, 3072L * 768);
    conv(ft_W2, w2t, 768L * 3072);
    conv(fp_W,  wp,  768L * 1536);
    conv(text,  text_bf, (long)BROWS * 768);

    // ---- image path: att = text@Wc.T + bc + image ; LN1 ----
    gemm(text_bf, 768, wc_it, BROWS, 768, 768, bc_it,
         image, 768, nullptr, 0, sbuf, 768, nullptr, 0, 0);
    ln(sbuf, ln_img_g, ln_img_b, nullptr, vbuf, 768, 0);
    ffn(vbuf, w1i, fi_b1, w2i, fi_b2, fused, 1536);   // -> fused[:, :768]
    // ---- text path: kv = post-FFN img (fused left half) ----
    gemm(fused, 1536, wc_ti, BROWS, 768, 768, bc_ti,
         text, 768, nullptr, 0, sbuf, 768, nullptr, 0, 0);
    ln(sbuf, ln_txt_g, ln_txt_b, nullptr, vbuf, 768, 0);
    ffn(vbuf, w1t, ft_b1, w2t, ft_b2, fused + 768, 1536);  // -> fused[:, 768:]
    // ---- final projection + LN + gelu ----
    gemm(fused, 1536, wp, BROWS, 768, 1536, fp_b,
         nullptr, 0, nullptr, 0, sbuf, 768, nullptr, 0, 0);
    ln(sbuf, fp_ln_g, fp_ln_b, (float*)d_out, nullptr, 0, 1);
}

// Round 4
// 1358.585 us; speedup vs baseline: 1.4116x; 1.0317x over previous
//
#include <hip/hip_runtime.h>
#include <hip/hip_bf16.h>
#include <math.h>

// CrossAttentionFusion on MI355X.
// softmax over one key == 1  =>  mha1(q_in, kv) = kv@Wc.T + bc,
//   Wc = Wo@Wv (fused once), bc = Wo@bv + bo.
// 2 tiny weight-combine GEMMs + 7 bf16-MFMA GEMMs + 3 layernorms.
// GEMM: 128x128 tile, BK=32, double-buffered LDS via global_load_lds(16B).
// Epilogue gelu = sigmoid-form tanh approx (v_exp+v_rcp, ~7 VALU ops) --
// erff was ~30+ ops and made the FFN-W1 GEMM VALU-bound (R3: VALUBusy 35%).

typedef unsigned short u16;
typedef __bf16 bf16_t;
typedef bf16_t bf16x8 __attribute__((ext_vector_type(8)));
typedef float f32x4 __attribute__((ext_vector_type(4)));

#define BROWS 16384   // batch
#define EDIM  768

__device__ __forceinline__ u16 f2bf(float f) {
    union { float f; unsigned u; } v; v.f = f;
    return (u16)((v.u + 0x7FFFu + ((v.u >> 16) & 1u)) >> 16);  // RNE
}
__device__ __forceinline__ float bf2f(u16 h) {
    union { unsigned u; float f; } v; v.u = ((unsigned)h) << 16;
    return v.f;
}
// gelu via x*sigmoid(1.5957691*x + 0.0713548*x^3); exp2/rcp HW instrs.
// |err vs exact| < ~2e-3, threshold is 9.8e-2.
__device__ __forceinline__ float gelu_f(float x) {
    float t = x * x;
    float p = fmaf(0.102943268f, t, 2.30221895f);   // log2(e) folded in
    float e = __builtin_amdgcn_exp2f(-x * p);
    return x * __builtin_amdgcn_rcpf(1.0f + e);
}

// async global->LDS, 16B/lane. LDS dest is wave-uniform base + lane*16.
__device__ __forceinline__ void gld16(const u16* g, u16* l) {
    __builtin_amdgcn_global_load_lds(
        (__attribute__((address_space(1))) void*)g,
        (__attribute__((address_space(3))) void*)l, 16, 0, 0);
}

// ---- batched f32->bf16 conversion: 8 tensors, one dispatch ----
struct ConvBatch {
    const float *s0, *s1, *s2, *s3, *s4, *s5, *s6, *s7;
    u16 *d0, *d1, *d2, *d3, *d4, *d5, *d6, *d7;
};
// blocks per segment (256 float4 per block): sizes/1024
#define CB0 2304   // fi_W1 3072*768
#define CB1 2304   // fi_W2
#define CB2 2304   // ft_W1
#define CB3 2304   // ft_W2
#define CB4 1152   // fp_W 768*1536
#define CB5 576    // it_Wo 768*768
#define CB6 576    // ti_Wo
#define CB7 12288  // text 16384*768
#define CONV_BLOCKS (CB0+CB1+CB2+CB3+CB4+CB5+CB6+CB7)

__global__ void __launch_bounds__(256) conv8_k(ConvBatch cb) {
    int b = blockIdx.x;
    const float* s; u16* d;
    if      (b < CB0)                          { s = cb.s0; d = cb.d0; }
    else if ((b -= CB0) < CB1)                 { s = cb.s1; d = cb.d1; }
    else if ((b -= CB1) < CB2)                 { s = cb.s2; d = cb.d2; }
    else if ((b -= CB2) < CB3)                 { s = cb.s3; d = cb.d3; }
    else if ((b -= CB3) < CB4)                 { s = cb.s4; d = cb.d4; }
    else if ((b -= CB4) < CB5)                 { s = cb.s5; d = cb.d5; }
    else if ((b -= CB5) < CB6)                 { s = cb.s6; d = cb.d6; }
    else    { b -= CB6;                          s = cb.s7; d = cb.d7; }
    int i = b * 256 + threadIdx.x;
    float4 v = ((const float4*)s)[i];
    ushort4 o;
    o.x = f2bf(v.x); o.y = f2bf(v.y); o.z = f2bf(v.z); o.w = f2bf(v.w);
    ((ushort4*)d)[i] = o;
}

// D[c,r] = bf16(S[r,c]) — transpose-convert (Wv.T for the weight combine).
__global__ void __launch_bounds__(256) f32_to_bf16_T_k(const float* __restrict__ S,
                                                       u16* __restrict__ D,
                                                       int R, int C) {
    __shared__ float t[32][33];
    const int r0 = blockIdx.y * 32, c0 = blockIdx.x * 32;
    const int tx = threadIdx.x & 31, ty = threadIdx.x >> 5;  // ty 0..7
#pragma unroll
    for (int i = ty; i < 32; i += 8) t[i][tx] = S[(long)(r0 + i) * C + c0 + tx];
    __syncthreads();
#pragma unroll
    for (int i = ty; i < 32; i += 8) D[(long)(c0 + i) * R + r0 + tx] = f2bf(t[tx][i]);
}

// bc[n] = bo[n] + dot(Wo[n,:], bv)
__global__ void __launch_bounds__(256) bias_comb_k(const float* __restrict__ Wo,
                                                   const float* __restrict__ bv,
                                                   const float* __restrict__ bo,
                                                   float* __restrict__ bc, int K) {
    const int n = blockIdx.x * 4 + (threadIdx.x >> 6);
    const int lane = threadIdx.x & 63;
    float s = 0.f;
    for (int k = lane; k < K; k += 64) s += Wo[(long)n * K + k] * bv[k];
#pragma unroll
    for (int o = 32; o > 0; o >>= 1) s += __shfl_down(s, o, 64);
    if (lane == 0) bc[n] = s + bo[n];
}

// C[m,n] = sum_k A[m,k] * W[n,k]  (+bias, +f32 or bf16 residual, opt gelu)
__global__ void __launch_bounds__(256) gemm_bt(
    const u16* __restrict__ A, int lda,
    const u16* __restrict__ W,
    const float* __restrict__ bias,
    const float* __restrict__ R, int ldr,      // f32 residual (or null)
    const u16* __restrict__ Rb, int ldrb,      // bf16 residual (or null)
    float* __restrict__ Cf, int ldcf,
    u16* __restrict__ Cb, int ldcb,
    int K, int do_gelu)
{
    __shared__ alignas(16) u16 sA[2][128 * 32];  // [buf][row*32+k], unpadded
    __shared__ alignas(16) u16 sB[2][128 * 32];

    const int tid  = threadIdx.x;
    const int lane = tid & 63;
    const int wave = tid >> 6;
    const int wm = wave >> 1;      // 0..1
    const int wn = wave & 1;       // 0..1
    const long m0 = (long)blockIdx.y * 128;
    const long n0 = (long)blockIdx.x * 128;

    // staging: each wave fills 2 chunks of 16 rows (1KB each) per matrix
    const int r  = lane >> 2;      // 0..15 row within chunk
    const int cb = lane & 3;       // 16B column block
    const int c0 = wave * 2, c1 = wave * 2 + 1;
    const u16* gA0 = A + (m0 + c0 * 16 + r) * (long)lda + cb * 8;
    const u16* gA1 = A + (m0 + c1 * 16 + r) * (long)lda + cb * 8;
    const u16* gB0 = W + (n0 + c0 * 16 + r) * (long)K + cb * 8;
    const u16* gB1 = W + (n0 + c1 * 16 + r) * (long)K + cb * 8;

    auto stage = [&](int buf, int kk) {
        gld16(gA0 + kk, sA[buf] + c0 * 512);
        gld16(gA1 + kk, sA[buf] + c1 * 512);
        gld16(gB0 + kk, sB[buf] + c0 * 512);
        gld16(gB1 + kk, sB[buf] + c1 * 512);
    };

    const int quad = lane >> 4;    // 0..3 -> k = quad*8 + j
    const int l16  = lane & 15;    // m (A) / n (B) index
    int offA[4], offB[4];
#pragma unroll
    for (int t = 0; t < 4; t++) {
        offA[t] = (wm * 64 + t * 16 + l16) * 32 + quad * 8;
        offB[t] = (wn * 64 + t * 16 + l16) * 32 + quad * 8;
    }

    f32x4 acc[4][4];
#pragma unroll
    for (int i = 0; i < 4; i++)
#pragma unroll
        for (int j = 0; j < 4; j++) {
            f32x4 z = {0.f, 0.f, 0.f, 0.f};
            acc[i][j] = z;
        }

    stage(0, 0);
    __syncthreads();               // prologue tile visible
    int buf = 0;
    for (int k0 = 0; k0 < K; k0 += 32) {
        const int nk = k0 + 32;
        if (nk < K) stage(buf ^ 1, nk);   // async prefetch overlaps compute
        bf16x8 af[4], bfr[4];
#pragma unroll
        for (int t = 0; t < 4; t++) af[t]  = *(const bf16x8*)(sA[buf] + offA[t]);
#pragma unroll
        for (int t = 0; t < 4; t++) bfr[t] = *(const bf16x8*)(sB[buf] + offB[t]);
#pragma unroll
        for (int mt = 0; mt < 4; mt++)
#pragma unroll
            for (int nt = 0; nt < 4; nt++)
                acc[mt][nt] = __builtin_amdgcn_mfma_f32_16x16x32_bf16(
                    af[mt], bfr[nt], acc[mt][nt], 0, 0, 0);
        __syncthreads();           // drains prefetch + guards buffer reuse
        buf ^= 1;
    }

    // epilogue: C/D layout col = lane&15, row = quad*4 + reg  [m89/m91]
#pragma unroll
    for (int mt = 0; mt < 4; mt++) {
#pragma unroll
        for (int nt = 0; nt < 4; nt++) {
            const long col = n0 + wn * 64 + nt * 16 + l16;
            const float bv = bias ? bias[col] : 0.0f;
#pragma unroll
            for (int rr = 0; rr < 4; rr++) {
                const long row = m0 + wm * 64 + mt * 16 + quad * 4 + rr;
                float v = acc[mt][nt][rr] + bv;
                if (R)  v += R[row * (long)ldr + col];
                if (Rb) v += bf2f(Rb[row * (long)ldrb + col]);
                if (do_gelu) v = gelu_f(v);
                if (Cf) Cf[row * (long)ldcf + col] = v;
                if (Cb) Cb[row * (long)ldcb + col] = f2bf(v);
            }
        }
    }
}

// LayerNorm over 768 cols, one block/row. Input bf16 (Xb) or f32 (Xf);
// output f32 (Yf) and/or bf16 (Yb); optional gelu. 192 active lanes x 4 elems.
__global__ void __launch_bounds__(256) ln_k(
    const u16*  __restrict__ Xb,
    const float* __restrict__ Xf,
    const float* __restrict__ g,
    const float* __restrict__ b,
    float* __restrict__ Yf,
    u16*   __restrict__ Yb,
    int do_gelu)
{
    const int row = blockIdx.x;
    const int tid = threadIdx.x;
    float v[4] = {0.f, 0.f, 0.f, 0.f};
    if (tid < 192) {
        if (Xb) {
            ushort4 u = ((const ushort4*)(Xb + (long)row * EDIM))[tid];
            v[0] = bf2f(u.x); v[1] = bf2f(u.y); v[2] = bf2f(u.z); v[3] = bf2f(u.w);
        } else {
            float4 f = ((const float4*)(Xf + (long)row * EDIM))[tid];
            v[0] = f.x; v[1] = f.y; v[2] = f.z; v[3] = f.w;
        }
    }
    float s = 0.f, s2 = 0.f;
#pragma unroll
    for (int j = 0; j < 4; j++) { s += v[j]; s2 += v[j] * v[j]; }
#pragma unroll
    for (int o = 32; o > 0; o >>= 1) {
        s  += __shfl_down(s,  o, 64);
        s2 += __shfl_down(s2, o, 64);
    }
    __shared__ float red[8];
    __shared__ float mb[2];
    const int wave = tid >> 6, lane = tid & 63;
    if (lane == 0) { red[wave] = s; red[4 + wave] = s2; }
    __syncthreads();
    if (tid == 0) {
        float S  = red[0] + red[1] + red[2] + red[3];
        float S2 = red[4] + red[5] + red[6] + red[7];
        float mean = S * (1.0f / 768.0f);
        float var  = S2 * (1.0f / 768.0f) - mean * mean;
        mb[0] = mean;
        mb[1] = rsqrtf(var + 1e-5f);
    }
    __syncthreads();
    if (tid < 192) {
        const float mean = mb[0], inv = mb[1];
        float y[4];
#pragma unroll
        for (int j = 0; j < 4; j++) {
            const int c = tid * 4 + j;
            y[j] = (v[j] - mean) * inv * g[c] + b[c];
            if (do_gelu) y[j] = gelu_f(y[j]);
        }
        if (Yf) {
            float4 o = {y[0], y[1], y[2], y[3]};
            ((float4*)(Yf + (long)row * EDIM))[tid] = o;
        }
        if (Yb) {
            ushort4 o = {f2bf(y[0]), f2bf(y[1]), f2bf(y[2]), f2bf(y[3])};
            ((ushort4*)(Yb + (long)row * EDIM))[tid] = o;
        }
    }
}

extern "C" void kernel_launch(void* const* d_in, const int* in_sizes, int n_in,
                              void* d_out, int out_size, void* d_ws, size_t ws_size,
                              hipStream_t stream) {
    (void)in_sizes; (void)n_in; (void)out_size;
    const float* image    = (const float*)d_in[0];
    const float* text     = (const float*)d_in[1];
    const float* it_Wv    = (const float*)d_in[4];
    const float* it_Wo    = (const float*)d_in[5];
    const float* it_bv    = (const float*)d_in[8];
    const float* it_bo    = (const float*)d_in[9];
    const float* ti_Wv    = (const float*)d_in[12];
    const float* ti_Wo    = (const float*)d_in[13];
    const float* ti_bv    = (const float*)d_in[16];
    const float* ti_bo    = (const float*)d_in[17];
    const float* ln_img_g = (const float*)d_in[18];
    const float* ln_img_b = (const float*)d_in[19];
    const float* ln_txt_g = (const float*)d_in[20];
    const float* ln_txt_b = (const float*)d_in[21];
    const float* fp_ln_g  = (const float*)d_in[22];
    const float* fp_ln_b  = (const float*)d_in[23];
    const float* fi_W1    = (const float*)d_in[24];
    const float* fi_b1    = (const float*)d_in[25];
    const float* fi_W2    = (const float*)d_in[26];
    const float* fi_b2    = (const float*)d_in[27];
    const float* ft_W1    = (const float*)d_in[28];
    const float* ft_b1    = (const float*)d_in[29];
    const float* ft_W2    = (const float*)d_in[30];
    const float* ft_b2    = (const float*)d_in[31];
    const float* fp_W     = (const float*)d_in[32];
    const float* fp_b     = (const float*)d_in[33];

    char* ws = (char*)d_ws;
    size_t off = 0;
    auto alloc = [&](size_t bytes) {
        char* p = ws + off; off += (bytes + 255) & ~(size_t)255; return p;
    };
    // bf16 weights (~28 MB, live whole call)
    u16* wo_it = (u16*)alloc((size_t)768 * 768 * 2);
    u16* wvT_it= (u16*)alloc((size_t)768 * 768 * 2);
    u16* wc_it = (u16*)alloc((size_t)768 * 768 * 2);
    u16* wo_ti = (u16*)alloc((size_t)768 * 768 * 2);
    u16* wvT_ti= (u16*)alloc((size_t)768 * 768 * 2);
    u16* wc_ti = (u16*)alloc((size_t)768 * 768 * 2);
    u16* w1i   = (u16*)alloc((size_t)3072 * 768 * 2);
    u16* w2i   = (u16*)alloc((size_t)768 * 3072 * 2);
    u16* w1t   = (u16*)alloc((size_t)3072 * 768 * 2);
    u16* w2t   = (u16*)alloc((size_t)768 * 3072 * 2);
    u16* wp    = (u16*)alloc((size_t)768 * 1536 * 2);
    float* bc_it = (float*)alloc(768 * 4);
    float* bc_ti = (float*)alloc(768 * 4);
    // activations
    u16* vbuf  = (u16*)alloc((size_t)BROWS * 768 * 2);   // post-LN bf16
    u16* fused = (u16*)alloc((size_t)BROWS * 1536 * 2);  // [img | txt] bf16
    u16* text_bf = fused;     // alias: text_bf dead before fused is written
    // hbuf (FFN hidden, adaptive chunk) and pbuf (bf16 pre-LN) share a region:
    // disjoint lifetimes (pbuf: att-gemm->ln; hbuf: inside ffn only).
    int fch = 16384;
    while (fch > 2048 && off + (size_t)fch * 3072 * 2 > ws_size) fch >>= 1;
    size_t region = (size_t)fch * 3072 * 2;
    if (region < (size_t)BROWS * 768 * 2) region = (size_t)BROWS * 768 * 2;
    u16* hbuf = (u16*)alloc(region);
    u16* pbuf = hbuf;

    auto gemm = [&](const u16* A, int lda, const u16* W, int M, int N, int K,
                    const float* bias, const float* R, int ldr,
                    const u16* Rb, int ldrb,
                    float* Cf, int ldcf, u16* Cb, int ldcb, int dg) {
        gemm_bt<<<dim3(N / 128, M / 128), dim3(256), 0, stream>>>(
            A, lda, W, bias, R, ldr, Rb, ldrb, Cf, ldcf, Cb, ldcb, K, dg);
    };
    auto ffn = [&](const u16* xin, const u16* W1, const float* b1,
                   const u16* W2, const float* b2, u16* outp, int ldout) {
        for (int c = 0; c < BROWS / fch; c++) {
            const u16* xc = xin + (size_t)c * fch * 768;
            gemm(xc, 768, W1, fch, 3072, 768, b1,
                 nullptr, 0, nullptr, 0, nullptr, 0, hbuf, 3072, 1);
            gemm(hbuf, 3072, W2, fch, 768, 3072, b2,
                 nullptr, 0, xc, 768,
                 nullptr, 0, outp + (size_t)c * fch * ldout, ldout, 0);
        }
    };

    // ---- conversions: one batched dispatch ----
    ConvBatch cbt = { fi_W1, fi_W2, ft_W1, ft_W2, fp_W, it_Wo, ti_Wo, text,
                      w1i,   w2i,   w1t,   w2t,   wp,   wo_it, wo_ti, text_bf };
    conv8_k<<<dim3(CONV_BLOCKS), dim3(256), 0, stream>>>(cbt);
    // ---- weight combine: Wc = Wo@Wv (bf16), bc = Wo@bv + bo ----
    f32_to_bf16_T_k<<<dim3(24, 24), dim3(256), 0, stream>>>(it_Wv, wvT_it, 768, 768);
    gemm(wo_it, 768, wvT_it, 768, 768, 768, nullptr,
         nullptr, 0, nullptr, 0, nullptr, 0, wc_it, 768, 0);
    bias_comb_k<<<dim3(192), dim3(256), 0, stream>>>(it_Wo, it_bv, it_bo, bc_it, 768);
    f32_to_bf16_T_k<<<dim3(24, 24), dim3(256), 0, stream>>>(ti_Wv, wvT_ti, 768, 768);
    gemm(wo_ti, 768, wvT_ti, 768, 768, 768, nullptr,
         nullptr, 0, nullptr, 0, nullptr, 0, wc_ti, 768, 0);
    bias_comb_k<<<dim3(192), dim3(256), 0, stream>>>(ti_Wo, ti_bv, ti_bo, bc_ti, 768);

    // ---- image path: att = text@Wc.T + bc + image ; LN1 ----
    gemm(text_bf, 768, wc_it, BROWS, 768, 768, bc_it,
         image, 768, nullptr, 0, nullptr, 0, pbuf, 768, 0);
    ln_k<<<dim3(BROWS), dim3(256), 0, stream>>>(
        pbuf, nullptr, ln_img_g, ln_img_b, nullptr, vbuf, 0);
    ffn(vbuf, w1i, fi_b1, w2i, fi_b2, fused, 1536);   // -> fused[:, :768]
    // ---- text path: kv = post-FFN img (fused left half) ----
    gemm(fused, 1536, wc_ti, BROWS, 768, 768, bc_ti,
         text, 768, nullptr, 0, nullptr, 0, pbuf, 768, 0);
    ln_k<<<dim3(BROWS), dim3(256), 0, stream>>>(
        pbuf, nullptr, ln_txt_g, ln_txt_b, nullptr, vbuf, 0);
    ffn(vbuf, w1t, ft_b1, w2t, ft_b2, fused + 768, 1536);  // -> fused[:, 768:]
    // ---- final projection + LN + gelu ----
    gemm(fused, 1536, wp, BROWS, 768, 1536, fp_b,
         nullptr, 0, nullptr, 0, nullptr, 0, pbuf, 768, 0);
    ln_k<<<dim3(BROWS), dim3(256), 0, stream>>>(
        pbuf, nullptr, fp_ln_g, fp_ln_b, (float*)d_out, nullptr, 1);
}

// Round 5
// 1325.504 us; speedup vs baseline: 1.4468x; 1.0250x over previous
//
#include <hip/hip_runtime.h>
#include <hip/hip_bf16.h>
#include <math.h>

// CrossAttentionFusion on MI355X.
// softmax over one key == 1  =>  mha1(q_in, kv) = kv@Wc.T + bc,
//   Wc = Wo@Wv (fused once), bc = Wo@bv + bo.
// 2 tiny weight-combine GEMMs + 7 bf16-MFMA GEMMs + 3 layernorms.
// GEMM: 128x128 tile, BK=32, double-buffered LDS via global_load_lds(16B).
// R5: XCD-aware block swizzle (A-slab sharers co-resident on one XCD; R4
// showed FETCH=325MB vs 100MB ideal on W2) + XOR bank-swizzle of LDS tiles
// (R4: 9.4M conflict cycles = 8-way conflicts from 64B row stride).

typedef unsigned short u16;
typedef __bf16 bf16_t;
typedef bf16_t bf16x8 __attribute__((ext_vector_type(8)));
typedef float f32x4 __attribute__((ext_vector_type(4)));

#define BROWS 16384   // batch
#define EDIM  768

__device__ __forceinline__ u16 f2bf(float f) {
    union { float f; unsigned u; } v; v.f = f;
    return (u16)((v.u + 0x7FFFu + ((v.u >> 16) & 1u)) >> 16);  // RNE
}
__device__ __forceinline__ float bf2f(u16 h) {
    union { unsigned u; float f; } v; v.u = ((unsigned)h) << 16;
    return v.f;
}
// gelu via x*sigmoid(1.5957691*x + 0.0713548*x^3); exp2/rcp HW instrs.
__device__ __forceinline__ float gelu_f(float x) {
    float t = x * x;
    float p = fmaf(0.102943268f, t, 2.30221895f);   // log2(e) folded in
    float e = __builtin_amdgcn_exp2f(-x * p);
    return x * __builtin_amdgcn_rcpf(1.0f + e);
}

// async global->LDS, 16B/lane. LDS dest is wave-uniform base + lane*16.
__device__ __forceinline__ void gld16(const u16* g, u16* l) {
    __builtin_amdgcn_global_load_lds(
        (__attribute__((address_space(1))) void*)g,
        (__attribute__((address_space(3))) void*)l, 16, 0, 0);
}

// ---- batched f32->bf16 conversion: 8 tensors, one dispatch ----
struct ConvBatch {
    const float *s0, *s1, *s2, *s3, *s4, *s5, *s6, *s7;
    u16 *d0, *d1, *d2, *d3, *d4, *d5, *d6, *d7;
};
#define CB0 2304   // fi_W1 3072*768
#define CB1 2304   // fi_W2
#define CB2 2304   // ft_W1
#define CB3 2304   // ft_W2
#define CB4 1152   // fp_W 768*1536
#define CB5 576    // it_Wo 768*768
#define CB6 576    // ti_Wo
#define CB7 12288  // text 16384*768
#define CONV_BLOCKS (CB0+CB1+CB2+CB3+CB4+CB5+CB6+CB7)

__global__ void __launch_bounds__(256) conv8_k(ConvBatch cb) {
    int b = blockIdx.x;
    const float* s; u16* d;
    if      (b < CB0)          { s = cb.s0; d = cb.d0; }
    else if ((b -= CB0) < CB1) { s = cb.s1; d = cb.d1; }
    else if ((b -= CB1) < CB2) { s = cb.s2; d = cb.d2; }
    else if ((b -= CB2) < CB3) { s = cb.s3; d = cb.d3; }
    else if ((b -= CB3) < CB4) { s = cb.s4; d = cb.d4; }
    else if ((b -= CB4) < CB5) { s = cb.s5; d = cb.d5; }
    else if ((b -= CB5) < CB6) { s = cb.s6; d = cb.d6; }
    else    { b -= CB6;          s = cb.s7; d = cb.d7; }
    int i = b * 256 + threadIdx.x;
    float4 v = ((const float4*)s)[i];
    ushort4 o;
    o.x = f2bf(v.x); o.y = f2bf(v.y); o.z = f2bf(v.z); o.w = f2bf(v.w);
    ((ushort4*)d)[i] = o;
}

// D[c,r] = bf16(S[r,c]) — transpose-convert (Wv.T for the weight combine).
__global__ void __launch_bounds__(256) f32_to_bf16_T_k(const float* __restrict__ S,
                                                       u16* __restrict__ D,
                                                       int R, int C) {
    __shared__ float t[32][33];
    const int r0 = blockIdx.y * 32, c0 = blockIdx.x * 32;
    const int tx = threadIdx.x & 31, ty = threadIdx.x >> 5;  // ty 0..7
#pragma unroll
    for (int i = ty; i < 32; i += 8) t[i][tx] = S[(long)(r0 + i) * C + c0 + tx];
    __syncthreads();
#pragma unroll
    for (int i = ty; i < 32; i += 8) D[(long)(c0 + i) * R + r0 + tx] = f2bf(t[tx][i]);
}

// bc[n] = bo[n] + dot(Wo[n,:], bv)
__global__ void __launch_bounds__(256) bias_comb_k(const float* __restrict__ Wo,
                                                   const float* __restrict__ bv,
                                                   const float* __restrict__ bo,
                                                   float* __restrict__ bc, int K) {
    const int n = blockIdx.x * 4 + (threadIdx.x >> 6);
    const int lane = threadIdx.x & 63;
    float s = 0.f;
    for (int k = lane; k < K; k += 64) s += Wo[(long)n * K + k] * bv[k];
#pragma unroll
    for (int o = 32; o > 0; o >>= 1) s += __shfl_down(s, o, 64);
    if (lane == 0) bc[n] = s + bo[n];
}

// C[m,n] = sum_k A[m,k] * W[n,k]  (+bias, +f32 or bf16 residual, opt gelu)
__global__ void __launch_bounds__(256) gemm_bt(
    const u16* __restrict__ A, int lda,
    const u16* __restrict__ W,
    const float* __restrict__ bias,
    const float* __restrict__ R, int ldr,      // f32 residual (or null)
    const u16* __restrict__ Rb, int ldrb,      // bf16 residual (or null)
    float* __restrict__ Cf, int ldcf,
    u16* __restrict__ Cb, int ldcb,
    int K, int do_gelu)
{
    __shared__ alignas(16) u16 sA[2][128 * 32];  // [buf][row*32+k]
    __shared__ alignas(16) u16 sB[2][128 * 32];

    const int tid  = threadIdx.x;
    const int lane = tid & 63;
    const int wave = tid >> 6;
    const int wm = wave >> 1;      // 0..1
    const int wn = wave & 1;       // 0..1

    // XCD-aware swizzle: id%8 = XCD (round-robin dispatch). Give each XCD a
    // contiguous slab of row-tiles; sweep col-tiles fastest within the slab,
    // so all sharers of an A row-slab are co-resident on one XCD's L2.
    int bm, bn;
    {
        const int gx = gridDim.x, gy = gridDim.y;
        const int id = blockIdx.y * gx + blockIdx.x;
        if ((gy & 7) == 0) {
            const int xcd = id & 7, slot = id >> 3;
            bn = slot % gx;
            bm = (xcd * (gy >> 3)) + slot / gx;
        } else { bm = blockIdx.y; bn = blockIdx.x; }
    }
    const long m0 = (long)bm * 128;
    const long n0 = (long)bn * 128;

    // staging: each wave fills 2 chunks of 16 rows (1KB each) per matrix.
    // Bank swizzle: lane (r,cb) stages global k-block cb^((r>>1)&3) into LDS
    // slot (r,cb) (write side is HW lane-contiguous); reads un-XOR it.
    const int r   = lane >> 2;      // 0..15 row within chunk
    const int cb  = lane & 3;       // 16B column block (LDS slot)
    const int cbs = cb ^ ((r >> 1) & 3);   // global k-block staged by this lane
    const int c0 = wave * 2, c1 = wave * 2 + 1;
    const u16* gA0 = A + (m0 + c0 * 16 + r) * (long)lda + cbs * 8;
    const u16* gA1 = A + (m0 + c1 * 16 + r) * (long)lda + cbs * 8;
    const u16* gB0 = W + (n0 + c0 * 16 + r) * (long)K + cbs * 8;
    const u16* gB1 = W + (n0 + c1 * 16 + r) * (long)K + cbs * 8;

    auto stage = [&](int buf, int kk) {
        gld16(gA0 + kk, sA[buf] + c0 * 512);
        gld16(gA1 + kk, sA[buf] + c1 * 512);
        gld16(gB0 + kk, sB[buf] + c0 * 512);
        gld16(gB1 + kk, sB[buf] + c1 * 512);
    };

    const int quad = lane >> 4;    // 0..3 -> k = quad*8 + j
    const int l16  = lane & 15;    // m (A) / n (B) index
    int offA[4], offB[4];
#pragma unroll
    for (int t = 0; t < 4; t++) {
        const int rowA = wm * 64 + t * 16 + l16;
        const int rowB = wn * 64 + t * 16 + l16;
        offA[t] = rowA * 32 + (quad ^ ((rowA >> 1) & 3)) * 8;
        offB[t] = rowB * 32 + (quad ^ ((rowB >> 1) & 3)) * 8;
    }

    f32x4 acc[4][4];
#pragma unroll
    for (int i = 0; i < 4; i++)
#pragma unroll
        for (int j = 0; j < 4; j++) {
            f32x4 z = {0.f, 0.f, 0.f, 0.f};
            acc[i][j] = z;
        }

    stage(0, 0);
    __syncthreads();               // prologue tile visible
    int buf = 0;
    for (int k0 = 0; k0 < K; k0 += 32) {
        const int nk = k0 + 32;
        if (nk < K) stage(buf ^ 1, nk);   // async prefetch overlaps compute
        bf16x8 af[4], bfr[4];
#pragma unroll
        for (int t = 0; t < 4; t++) af[t]  = *(const bf16x8*)(sA[buf] + offA[t]);
#pragma unroll
        for (int t = 0; t < 4; t++) bfr[t] = *(const bf16x8*)(sB[buf] + offB[t]);
#pragma unroll
        for (int mt = 0; mt < 4; mt++)
#pragma unroll
            for (int nt = 0; nt < 4; nt++)
                acc[mt][nt] = __builtin_amdgcn_mfma_f32_16x16x32_bf16(
                    af[mt], bfr[nt], acc[mt][nt], 0, 0, 0);
        __syncthreads();           // drains prefetch + guards buffer reuse
        buf ^= 1;
    }

    // epilogue: C/D layout col = lane&15, row = quad*4 + reg  [m89/m91]
#pragma unroll
    for (int mt = 0; mt < 4; mt++) {
#pragma unroll
        for (int nt = 0; nt < 4; nt++) {
            const long col = n0 + wn * 64 + nt * 16 + l16;
            const float bv = bias ? bias[col] : 0.0f;
#pragma unroll
            for (int rr = 0; rr < 4; rr++) {
                const long row = m0 + wm * 64 + mt * 16 + quad * 4 + rr;
                float v = acc[mt][nt][rr] + bv;
                if (R)  v += R[row * (long)ldr + col];
                if (Rb) v += bf2f(Rb[row * (long)ldrb + col]);
                if (do_gelu) v = gelu_f(v);
                if (Cf) Cf[row * (long)ldcf + col] = v;
                if (Cb) Cb[row * (long)ldcb + col] = f2bf(v);
            }
        }
    }
}

// LayerNorm over 768 cols, one block/row. Input bf16 (Xb) or f32 (Xf);
// output f32 (Yf) and/or bf16 (Yb); optional gelu. 192 active lanes x 4 elems.
__global__ void __launch_bounds__(256) ln_k(
    const u16*  __restrict__ Xb,
    const float* __restrict__ Xf,
    const float* __restrict__ g,
    const float* __restrict__ b,
    float* __restrict__ Yf,
    u16*   __restrict__ Yb,
    int do_gelu)
{
    const int row = blockIdx.x;
    const int tid = threadIdx.x;
    float v[4] = {0.f, 0.f, 0.f, 0.f};
    if (tid < 192) {
        if (Xb) {
            ushort4 u = ((const ushort4*)(Xb + (long)row * EDIM))[tid];
            v[0] = bf2f(u.x); v[1] = bf2f(u.y); v[2] = bf2f(u.z); v[3] = bf2f(u.w);
        } else {
            float4 f = ((const float4*)(Xf + (long)row * EDIM))[tid];
            v[0] = f.x; v[1] = f.y; v[2] = f.z; v[3] = f.w;
        }
    }
    float s = 0.f, s2 = 0.f;
#pragma unroll
    for (int j = 0; j < 4; j++) { s += v[j]; s2 += v[j] * v[j]; }
#pragma unroll
    for (int o = 32; o > 0; o >>= 1) {
        s  += __shfl_down(s,  o, 64);
        s2 += __shfl_down(s2, o, 64);
    }
    __shared__ float red[8];
    __shared__ float mb[2];
    const int wave = tid >> 6, lane = tid & 63;
    if (lane == 0) { red[wave] = s; red[4 + wave] = s2; }
    __syncthreads();
    if (tid == 0) {
        float S  = red[0] + red[1] + red[2] + red[3];
        float S2 = red[4] + red[5] + red[6] + red[7];
        float mean = S * (1.0f / 768.0f);
        float var  = S2 * (1.0f / 768.0f) - mean * mean;
        mb[0] = mean;
        mb[1] = rsqrtf(var + 1e-5f);
    }
    __syncthreads();
    if (tid < 192) {
        const float mean = mb[0], inv = mb[1];
        float y[4];
#pragma unroll
        for (int j = 0; j < 4; j++) {
            const int c = tid * 4 + j;
            y[j] = (v[j] - mean) * inv * g[c] + b[c];
            if (do_gelu) y[j] = gelu_f(y[j]);
        }
        if (Yf) {
            float4 o = {y[0], y[1], y[2], y[3]};
            ((float4*)(Yf + (long)row * EDIM))[tid] = o;
        }
        if (Yb) {
            ushort4 o = {f2bf(y[0]), f2bf(y[1]), f2bf(y[2]), f2bf(y[3])};
            ((ushort4*)(Yb + (long)row * EDIM))[tid] = o;
        }
    }
}

extern "C" void kernel_launch(void* const* d_in, const int* in_sizes, int n_in,
                              void* d_out, int out_size, void* d_ws, size_t ws_size,
                              hipStream_t stream) {
    (void)in_sizes; (void)n_in; (void)out_size;
    const float* image    = (const float*)d_in[0];
    const float* text     = (const float*)d_in[1];
    const float* it_Wv    = (const float*)d_in[4];
    const float* it_Wo    = (const float*)d_in[5];
    const float* it_bv    = (const float*)d_in[8];
    const float* it_bo    = (const float*)d_in[9];
    const float* ti_Wv    = (const float*)d_in[12];
    const float* ti_Wo    = (const float*)d_in[13];
    const float* ti_bv    = (const float*)d_in[16];
    const float* ti_bo    = (const float*)d_in[17];
    const float* ln_img_g = (const float*)d_in[18];
    const float* ln_img_b = (const float*)d_in[19];
    const float* ln_txt_g = (const float*)d_in[20];
    const float* ln_txt_b = (const float*)d_in[21];
    const float* fp_ln_g  = (const float*)d_in[22];
    const float* fp_ln_b  = (const float*)d_in[23];
    const float* fi_W1    = (const float*)d_in[24];
    const float* fi_b1    = (const float*)d_in[25];
    const float* fi_W2    = (const float*)d_in[26];
    const float* fi_b2    = (const float*)d_in[27];
    const float* ft_W1    = (const float*)d_in[28];
    const float* ft_b1    = (const float*)d_in[29];
    const float* ft_W2    = (const float*)d_in[30];
    const float* ft_b2    = (const float*)d_in[31];
    const float* fp_W     = (const float*)d_in[32];
    const float* fp_b     = (const float*)d_in[33];

    char* ws = (char*)d_ws;
    size_t off = 0;
    auto alloc = [&](size_t bytes) {
        char* p = ws + off; off += (bytes + 255) & ~(size_t)255; return p;
    };
    // bf16 weights (~28 MB, live whole call)
    u16* wo_it = (u16*)alloc((size_t)768 * 768 * 2);
    u16* wvT_it= (u16*)alloc((size_t)768 * 768 * 2);
    u16* wc_it = (u16*)alloc((size_t)768 * 768 * 2);
    u16* wo_ti = (u16*)alloc((size_t)768 * 768 * 2);
    u16* wvT_ti= (u16*)alloc((size_t)768 * 768 * 2);
    u16* wc_ti = (u16*)alloc((size_t)768 * 768 * 2);
    u16* w1i   = (u16*)alloc((size_t)3072 * 768 * 2);
    u16* w2i   = (u16*)alloc((size_t)768 * 3072 * 2);
    u16* w1t   = (u16*)alloc((size_t)3072 * 768 * 2);
    u16* w2t   = (u16*)alloc((size_t)768 * 3072 * 2);
    u16* wp    = (u16*)alloc((size_t)768 * 1536 * 2);
    float* bc_it = (float*)alloc(768 * 4);
    float* bc_ti = (float*)alloc(768 * 4);
    // activations
    u16* vbuf  = (u16*)alloc((size_t)BROWS * 768 * 2);   // post-LN bf16
    u16* fused = (u16*)alloc((size_t)BROWS * 1536 * 2);  // [img | txt] bf16
    u16* text_bf = fused;     // alias: text_bf dead before fused is written
    // hbuf (FFN hidden, adaptive chunk) and pbuf (bf16 pre-LN) share a region.
    int fch = 16384;
    while (fch > 2048 && off + (size_t)fch * 3072 * 2 > ws_size) fch >>= 1;
    size_t region = (size_t)fch * 3072 * 2;
    if (region < (size_t)BROWS * 768 * 2) region = (size_t)BROWS * 768 * 2;
    u16* hbuf = (u16*)alloc(region);
    u16* pbuf = hbuf;

    auto gemm = [&](const u16* A, int lda, const u16* W, int M, int N, int K,
                    const float* bias, const float* R, int ldr,
                    const u16* Rb, int ldrb,
                    float* Cf, int ldcf, u16* Cb, int ldcb, int dg) {
        gemm_bt<<<dim3(N / 128, M / 128), dim3(256), 0, stream>>>(
            A, lda, W, bias, R, ldr, Rb, ldrb, Cf, ldcf, Cb, ldcb, K, dg);
    };
    auto ffn = [&](const u16* xin, const u16* W1, const float* b1,
                   const u16* W2, const float* b2, u16* outp, int ldout) {
        for (int c = 0; c < BROWS / fch; c++) {
            const u16* xc = xin + (size_t)c * fch * 768;
            gemm(xc, 768, W1, fch, 3072, 768, b1,
                 nullptr, 0, nullptr, 0, nullptr, 0, hbuf, 3072, 1);
            gemm(hbuf, 3072, W2, fch, 768, 3072, b2,
                 nullptr, 0, xc, 768,
                 nullptr, 0, outp + (size_t)c * fch * ldout, ldout, 0);
        }
    };

    // ---- conversions: one batched dispatch ----
    ConvBatch cbt = { fi_W1, fi_W2, ft_W1, ft_W2, fp_W, it_Wo, ti_Wo, text,
                      w1i,   w2i,   w1t,   w2t,   wp,   wo_it, wo_ti, text_bf };
    conv8_k<<<dim3(CONV_BLOCKS), dim3(256), 0, stream>>>(cbt);
    // ---- weight combine: Wc = Wo@Wv (bf16), bc = Wo@bv + bo ----
    f32_to_bf16_T_k<<<dim3(24, 24), dim3(256), 0, stream>>>(it_Wv, wvT_it, 768, 768);
    gemm(wo_it, 768, wvT_it, 768, 768, 768, nullptr,
         nullptr, 0, nullptr, 0, nullptr, 0, wc_it, 768, 0);
    bias_comb_k<<<dim3(192), dim3(256), 0, stream>>>(it_Wo, it_bv, it_bo, bc_it, 768);
    f32_to_bf16_T_k<<<dim3(24, 24), dim3(256), 0, stream>>>(ti_Wv, wvT_ti, 768, 768);
    gemm(wo_ti, 768, wvT_ti, 768, 768, 768, nullptr,
         nullptr, 0, nullptr, 0, nullptr, 0, wc_ti, 768, 0);
    bias_comb_k<<<dim3(192), dim3(256), 0, stream>>>(ti_Wo, ti_bv, ti_bo, bc_ti, 768);

    // ---- image path: att = text@Wc.T + bc + image ; LN1 ----
    gemm(text_bf, 768, wc_it, BROWS, 768, 768, bc_it,
         image, 768, nullptr, 0, nullptr, 0, pbuf, 768, 0);
    ln_k<<<dim3(BROWS), dim3(256), 0, stream>>>(
        pbuf, nullptr, ln_img_g, ln_img_b, nullptr, vbuf, 0);
    ffn(vbuf, w1i, fi_b1, w2i, fi_b2, fused, 1536);   // -> fused[:, :768]
    // ---- text path: kv = post-FFN img (fused left half) ----
    gemm(fused, 1536, wc_ti, BROWS, 768, 768, bc_ti,
         text, 768, nullptr, 0, nullptr, 0, pbuf, 768, 0);
    ln_k<<<dim3(BROWS), dim3(256), 0, stream>>>(
        pbuf, nullptr, ln_txt_g, ln_txt_b, nullptr, vbuf, 0);
    ffn(vbuf, w1t, ft_b1, w2t, ft_b2, fused + 768, 1536);  // -> fused[:, 768:]
    // ---- final projection + LN + gelu ----
    gemm(fused, 1536, wp, BROWS, 768, 1536, fp_b,
         nullptr, 0, nullptr, 0, nullptr, 0, pbuf, 768, 0);
    ln_k<<<dim3(BROWS), dim3(256), 0, stream>>>(
        pbuf, nullptr, fp_ln_g, fp_ln_b, (float*)d_out, nullptr, 1);
}